// Round 3
// baseline (470.632 us; speedup 1.0000x reference)
//
#include <hip/hip_runtime.h>

// PLIF scan: v[t] = (v[t-1]*decay + x[t]) with zero-reset at v >= 1.0.
// T=16, spatial = 4194304 elements, fp32. Pure streaming kernel.
//
// Round-1 lesson: naive unrolled loop compiled to load->wait->store per
// timestep (VGPR=32, 1 load in flight) -> latency-bound at 2.4 TB/s.
// Fix: prefetch ALL 16 timestep values into registers (16 independent
// 16B loads in flight per wave), then compute the scan chain and store
// with nontemporal hint (output is never re-read).
// Round-2 fix: __builtin_nontemporal_store needs a clang native vector,
// not HIP_vector_type float4 -> use ext_vector_type(4).

#define T_STEPS 16
#define V_THRESHOLD 1.0f

typedef float v4f __attribute__((ext_vector_type(4)));

__global__ __launch_bounds__(256) void plif_kernel(
    const v4f* __restrict__ x,        // [T, SPATIAL/4]
    const float* __restrict__ decay,  // [1]
    v4f* __restrict__ out,            // [T, SPATIAL/4]
    long long stride4)                // SPATIAL/4
{
    const long long idx = (long long)blockIdx.x * blockDim.x + threadIdx.x;
    if (idx >= stride4) return;
    const float d = decay[0];

    // Phase 1: 16 independent loads — all in flight simultaneously.
    v4f xs[T_STEPS];
#pragma unroll
    for (int t = 0; t < T_STEPS; ++t) {
        xs[t] = x[idx + (long long)t * stride4];
    }

    // Phase 2: scan chain (trivial VALU) + nontemporal stores.
    v4f v = (v4f)(0.f);
#pragma unroll
    for (int t = 0; t < T_STEPS; ++t) {
        const v4f x4 = xs[t];
        v.x = fmaf(v.x, d, x4.x); if (v.x >= V_THRESHOLD) v.x = 0.f;
        v.y = fmaf(v.y, d, x4.y); if (v.y >= V_THRESHOLD) v.y = 0.f;
        v.z = fmaf(v.z, d, x4.z); if (v.z >= V_THRESHOLD) v.z = 0.f;
        v.w = fmaf(v.w, d, x4.w); if (v.w >= V_THRESHOLD) v.w = 0.f;
        __builtin_nontemporal_store(v, &out[idx + (long long)t * stride4]);
    }
}

extern "C" void kernel_launch(void* const* d_in, const int* in_sizes, int n_in,
                              void* d_out, int out_size, void* d_ws, size_t ws_size,
                              hipStream_t stream) {
    const float* x     = (const float*)d_in[0];   // [T,N,C,H,W] fp32
    const float* decay = (const float*)d_in[1];   // [1] fp32
    float* out         = (float*)d_out;           // [T,N,C,H,W] fp32

    const long long total   = in_sizes[0];        // T * SPATIAL
    const long long spatial = total / T_STEPS;    // 4194304
    const long long stride4 = spatial / 4;        // 1048576 float4/timestep

    const int block = 256;
    const int grid  = (int)((stride4 + block - 1) / block);  // 4096

    plif_kernel<<<grid, block, 0, stream>>>(
        (const v4f*)x, decay, (v4f*)out, stride4);
}